// Round 13
// baseline (741.513 us; speedup 1.0000x reference)
//
#include <hip/hip_runtime.h>
#include <cmath>

// ---- TwinsBlock: B=32, H=W=56, C=256, heads=8, ws=7. fp32 I/O, bf16 MFMA ----
// R13: mlp_fused occupancy fix. R12 diagnosis: per-phase work ~1k cy but
// phases take ~5.5k cy — only 2 blocks/CU resident (80KB LDS), so barrier
// drains are unhidden. Fix: X fragments are per-wave private (32 VGPR) ->
// preload once from pre-swizzled xn into registers, DELETE lX. LDS 80->48KB
// -> 3 blocks/CU (12 waves, +50% TLP), same 9 barriers/nc, phase A loses its
// lX ds_reads. launch_bounds(256,3) -> VGPR cap 170 under either arg2
// interpretation (need ~166). attn setprio REVERTED (R12 total regressed;
// m190: setprio hurts barrier-synced blocks). All else R12/R10-verbatim.
typedef __bf16 bf16;
typedef __bf16 bf16x4 __attribute__((ext_vector_type(4)));
typedef __bf16 bf16x8 __attribute__((ext_vector_type(8)));
typedef float floatx4 __attribute__((ext_vector_type(4)));

constexpr int BATCH = 32;
constexpr int NTOK  = 3136;            // 56*56
constexpr int CDIM  = 256;
constexpr int MROWS = BATCH * NTOK;    // 100352
constexpr int HIDD  = 1024;
constexpr float ATTN_SCALE = 0.17677669529663689f;  // 32^-0.5

// tanh-form GELU: x * sigmoid(1.5957691*(x + 0.044715 x^3)).
__device__ __forceinline__ float gelu_fast(float x) {
    float p = fmaf(0.044715f * x, x * x, x);
    return __fdividef(x, 1.0f + __expf(-1.5957691216057308f * p));
}

__device__ __forceinline__ void load8(const bf16* p, float* o) {
    bf16x8 v = *reinterpret_cast<const bf16x8*>(p);
#pragma unroll
    for (int j = 0; j < 8; j++) o[j] = (float)v[j];
}

// async global->LDS, 16B per lane, wave-uniform LDS base + lane*16
__device__ __forceinline__ void gload_lds16(const void* g, void* l) {
    __builtin_amdgcn_global_load_lds(
        (const __attribute__((address_space(1))) void*)g,
        (__attribute__((address_space(3))) void*)l, 16, 0, 0);
}

// ---------------- weight convert + transpose: fp32 [K,N] -> bf16 [N,K] ----------------
// gsc: fold mlp_ln_g into fc2 rows. swz: pre-swizzle k by ((n&7)<<3) (8-elem granule).
__global__ __launch_bounds__(256) void wt_kernel(
    const float* __restrict__ Win, bf16* __restrict__ Wt, int Ksz, int Nsz,
    const float* __restrict__ gsc, int swz)
{
    int id = blockIdx.x * 256 + threadIdx.x;
    int n = id / Ksz, k = id % Ksz;
    float v = Win[(size_t)k * Nsz + n];
    if (gsc) v *= gsc[k];
    int kp = k ^ (swz & ((n & 7) << 3));
    Wt[(size_t)n * Ksz + kp] = (bf16)v;
}

// ---------------- c1/c2 column corrections for folded mlp-LN ----------------
__global__ __launch_bounds__(256) void c12_part_kernel(
    const float* __restrict__ W, const float* __restrict__ g,
    const float* __restrict__ b, float2* __restrict__ part)   // part[16][256]
{
    int n = threadIdx.x, j = blockIdx.x;
    float c1 = 0.f, c2 = 0.f;
#pragma unroll 8
    for (int k = j * 64; k < j * 64 + 64; k++) {
        float w = W[(size_t)k * 256 + n];
        c1 = fmaf(b[k], w, c1);
        c2 = fmaf(g[k], w, c2);
    }
    part[j * 256 + n] = make_float2(c1, c2);
}

__global__ __launch_bounds__(256) void c12_red_kernel(
    const float2* __restrict__ part, float2* __restrict__ c12)
{
    int n = threadIdx.x;
    float c1 = 0.f, c2 = 0.f;
#pragma unroll
    for (int j = 0; j < 16; j++) { float2 p = part[j * 256 + n]; c1 += p.x; c2 += p.y; }
    c12[n] = make_float2(c1, c2);
}

// ---------------- fused LN (stats+apply): fp32 [M,256] -> bf16 [M,256] ----------------
// swz: pre-swizzle output cols by ((tok&7)<<3) so GEMM ds_reads are conflict-free.
__global__ __launch_bounds__(256) void ln_apply_f32_kernel(
    const float* __restrict__ X, const float* __restrict__ g,
    const float* __restrict__ b, bf16* __restrict__ Y, int swz)
{
    int tok  = (blockIdx.x * 256 + threadIdx.x) >> 6;   // one wave per token
    int lane = threadIdx.x & 63;
    const float* row = X + (size_t)tok * CDIM;
    float4 v = *reinterpret_cast<const float4*>(row + lane * 4);
    float s  = v.x + v.y + v.z + v.w;
    float ss = v.x * v.x + v.y * v.y + v.z * v.z + v.w * v.w;
#pragma unroll
    for (int off = 32; off > 0; off >>= 1) {
        s  += __shfl_xor(s,  off, 64);
        ss += __shfl_xor(ss, off, 64);
    }
    float mean = s * (1.0f / CDIM);
    float var  = ss * (1.0f / CDIM) - mean * mean;
    if (var < 0.f) var = 0.f;
    float rstd = rsqrtf(var + 1e-5f);
    float4 gg = *reinterpret_cast<const float4*>(g + lane * 4);
    float4 bb = *reinterpret_cast<const float4*>(b + lane * 4);
    bf16x4 o;
    o[0] = (bf16)((v.x - mean) * rstd * gg.x + bb.x);
    o[1] = (bf16)((v.y - mean) * rstd * gg.y + bb.y);
    o[2] = (bf16)((v.z - mean) * rstd * gg.z + bb.z);
    o[3] = (bf16)((v.w - mean) * rstd * gg.w + bb.w);
    int off4 = (lane * 4) ^ (swz & ((tok & 7) << 3));   // 4-granule preserved
    *reinterpret_cast<bf16x4*>(Y + (size_t)tok * CDIM + off4) = o;
}

// ---------------- fallback: fused LN in-place over bf16 [M,1024] ----------------
__global__ __launch_bounds__(256) void ln_inplace_h_kernel(
    bf16* __restrict__ H, const float* __restrict__ g, const float* __restrict__ b)
{
    int tok  = (blockIdx.x * 256 + threadIdx.x) >> 6;
    int lane = threadIdx.x & 63;
    bf16* row = H + (size_t)tok * HIDD;
    float f[16];
    load8(row + lane * 8, f);
    load8(row + 512 + lane * 8, f + 8);
    float s = 0.f, ss = 0.f;
#pragma unroll
    for (int j = 0; j < 16; j++) { s += f[j]; ss += f[j] * f[j]; }
#pragma unroll
    for (int off = 32; off > 0; off >>= 1) {
        s  += __shfl_xor(s,  off, 64);
        ss += __shfl_xor(ss, off, 64);
    }
    float mean = s * (1.0f / HIDD);
    float var  = ss * (1.0f / HIDD) - mean * mean;
    if (var < 0.f) var = 0.f;
    float rstd = rsqrtf(var + 1e-5f);
    bf16x8 o0, o1;
#pragma unroll
    for (int j = 0; j < 8; j++) {
        o0[j] = (bf16)((f[j]     - mean) * rstd * g[lane * 8 + j]       + b[lane * 8 + j]);
        o1[j] = (bf16)((f[j + 8] - mean) * rstd * g[512 + lane * 8 + j] + b[512 + lane * 8 + j]);
    }
    *reinterpret_cast<bf16x8*>(row + lane * 8) = o0;
    *reinterpret_cast<bf16x8*>(row + 512 + lane * 8) = o1;
}

// ---------------- m97-style GEMM: out = epi( A[M,K] @ Bt[N,K]^T + bias ) ----------------
// EPI 0: bias. EPI 1: bias+GELU. EPI 3: bias+resid.
// SWZ: A/Bt are pre-swizzled (8-elem granule by row&7) -> XOR on fragment reads.
template<int EPI, bool SWZ, typename TO>
__global__ __launch_bounds__(256) void gemm_bt_kernel(
    const bf16* __restrict__ A, const bf16* __restrict__ Bt,
    const float* __restrict__ bias, const float* __restrict__ resid,
    TO* __restrict__ out, int Nsz, int Ksz)
{
    __shared__ bf16 lA[128 * 64];
    __shared__ bf16 lB[128 * 64];
    const int t = threadIdx.x;
    const int lane = t & 63, w = t >> 6;
    const int quad = lane >> 4, l16 = lane & 15;
    const int wm = (w >> 1) * 64, wn = (w & 1) * 64;

    const int gx   = gridDim.x;
    const int flat = blockIdx.y * gx + blockIdx.x;
    const int cpx  = (gx * gridDim.y) >> 3;
    const int fl2  = (flat & 7) * cpx + (flat >> 3);   // bijective (nwg%8==0)
    const int bx   = fl2 % gx, by = fl2 / gx;

    const size_t m0 = (size_t)by * 128;
    const int n0 = bx * 128;
    const int srow = w * 32 + (lane >> 3);
    const int scol = (lane & 7) * 8;
    const int swzr = SWZ ? ((l16 & 7) << 3) : 0;   // frag-row&7 == l16&7

    floatx4 acc[4][4] = {};

    for (int kc = 0; kc < Ksz; kc += 64) {
#pragma unroll
        for (int j = 0; j < 4; j++) {
            gload_lds16(A  + (m0 + srow + j * 8) * Ksz + kc + scol, &lA[(w * 32 + j * 8) * 64]);
            gload_lds16(Bt + (size_t)(n0 + srow + j * 8) * Ksz + kc + scol, &lB[(w * 32 + j * 8) * 64]);
        }
        __syncthreads();
#pragma unroll
        for (int ks = 0; ks < 64; ks += 32) {
            bf16x8 af[4], bfv[4];
#pragma unroll
            for (int i = 0; i < 4; i++) {
                af[i]  = *reinterpret_cast<const bf16x8*>(&lA[(wm + i * 16 + l16) * 64 + ((ks + quad * 8) ^ swzr)]);
                bfv[i] = *reinterpret_cast<const bf16x8*>(&lB[(wn + i * 16 + l16) * 64 + ((ks + quad * 8) ^ swzr)]);
            }
#pragma unroll
            for (int mi = 0; mi < 4; mi++)
#pragma unroll
                for (int ni = 0; ni < 4; ni++)
                    acc[mi][ni] = __builtin_amdgcn_mfma_f32_16x16x32_bf16(af[mi], bfv[ni], acc[mi][ni], 0, 0, 0);
        }
        __syncthreads();
    }

#pragma unroll
    for (int mi = 0; mi < 4; mi++) {
#pragma unroll
        for (int ni = 0; ni < 4; ni++) {
            int col = n0 + wn + ni * 16 + l16;
            float bcol = bias[col];
#pragma unroll
            for (int r = 0; r < 4; r++) {
                size_t row = m0 + wm + mi * 16 + quad * 4 + r;
                float v = acc[mi][ni][r] + bcol;
                if (EPI == 1) v = gelu_fast(v);
                if (EPI == 3) v += resid[row * (size_t)Nsz + col];
                out[row * (size_t)Nsz + col] = (TO)v;
            }
        }
    }
}

// ---------------- fused MLP: out = resid + LN(gelu(xn@W1+b1))@W2g + b2 ----------------
// 64-row tile, 4 waves. X fragments preloaded to REGISTERS (32 VGPR/lane,
// from pre-swizzled xn). Per nc (8 chunks of 128 hid):
//   phase A: 2 x {stage lW1[128][128], barrier, 4 ks x 8 MFMA (xf from regs), barrier}
//   gelu+stats in regs -> bf16x4 -> XOR-swizzled lH[64][128]; barrier
//   phase B: 2 x {stage lW2[256][64], barrier, 32 MFMA, barrier}
// LDS 48KB (lP 32 + lH 16, lstats aliases lP) -> 3 blocks/CU, 12 waves.
__global__ __launch_bounds__(256, 3) void mlp_fused_kernel(
    const bf16* __restrict__ A,      // xn [M][256], pre-swizzled
    const bf16* __restrict__ W1t,    // [1024][256], pre-swizzled
    const bf16* __restrict__ W2t,    // [256][1024], pre-swizzled, g-folded
    const float* __restrict__ b1, const float* __restrict__ b2,
    const float* __restrict__ resid, const float2* __restrict__ c12,
    float* __restrict__ out)
{
    __shared__ bf16 lP[16384];          // 32KB: lW1[128][128] | lW2[256][64] | lstats
    __shared__ bf16 lH[64 * 128];       // 16KB, [tok][hid] XOR-swizzled

    const int t = threadIdx.x;
    const int lane = t & 63, w = t >> 6;
    const int quad = lane >> 4, l16 = lane & 15;
    const int whid  = (w >> 1) * 64, wtok1 = (w & 1) * 32;   // GEMM1 roles
    const int wtok2 = (w >> 1) * 32, wout  = (w & 1) * 128;  // GEMM2 roles

    const int cpx = gridDim.x >> 3;            // 1568/8 = 196
    const int bid = (blockIdx.x & 7) * cpx + (blockIdx.x >> 3);
    const size_t m0 = (size_t)bid * 64;

    const int srow = t >> 4;                   // 0..15 (lW1 staging, 16 lanes/row)
    const int schk = (t & 15) * 8;
    const int lrow = lane >> 3;                // lW2 staging: 8 lanes/row
    const int scol = (lane & 7) * 8;
    const int swzr = (l16 & 7) << 3;

    bf16* lW1 = lP;                            // [128][128]
    bf16* lW2 = lP;                            // [256][64]
    float2* lstats = (float2*)lP;              // [64][2], epilogue only

    // ---- preload X fragments to registers: xreg[tok-grp][k8] (32 VGPR) ----
    // logical (tok, col k8*32+quad*8 .. +8); xn pre-swizzled by (tok&7)*8,
    // tok == l16 (mod 8) so XOR key = swzr. 16 x 16B loads per lane.
    bf16x8 xreg[2][8];
#pragma unroll
    for (int i = 0; i < 2; i++) {
        const bf16* xrow = A + (m0 + wtok1 + i * 16 + l16) * 256;
#pragma unroll
        for (int k8 = 0; k8 < 8; k8++)
            xreg[i][k8] = *reinterpret_cast<const bf16x8*>(
                xrow + ((k8 * 32 + quad * 8) ^ swzr));
    }

    floatx4 acc2[2][8] = {};                   // U: [tok-mi][out-ni]
    float tsum[2] = {0.f, 0.f};
    float tss[2]  = {0.f, 0.f};

    for (int nc = 0; nc < 8; nc++) {
        // ---- phase A: Hc^T = (xn @ W1 chunk)^T, two K=128 sub-chunks ----
        floatx4 sT[4][2] = {};                 // [hid-mt][tok-nt]
#pragma unroll
        for (int kc2 = 0; kc2 < 2; kc2++) {
            const int kc = kc2 * 128;
#pragma unroll
            for (int j = 0; j < 8; j++)        // lW1: 128 rows x 128 cols
                gload_lds16(W1t + (size_t)(nc * 128 + j * 16 + srow) * 256 + kc + schk,
                            &lW1[(j * 16 + w * 4) * 128]);
            __syncthreads();
#pragma unroll
            for (int ksi = 0; ksi < 4; ksi++) {
                const int ks = ksi * 32;
                bf16x8 wf[4];
#pragma unroll
                for (int i = 0; i < 4; i++)
                    wf[i] = *reinterpret_cast<const bf16x8*>(
                        &lW1[(whid + i * 16 + l16) * 128 + ((ks + quad * 8) ^ swzr)]);
#pragma unroll
                for (int mt = 0; mt < 4; mt++)
#pragma unroll
                    for (int nt = 0; nt < 2; nt++)
                        sT[mt][nt] = __builtin_amdgcn_mfma_f32_16x16x32_bf16(
                            wf[mt], xreg[nt][kc2 * 4 + ksi], sT[mt][nt], 0, 0, 0);
            }
            __syncthreads();
        }
        // ---- bias + gelu + stats + pack -> lH[tok][hid^swz] ----
#pragma unroll
        for (int mt = 0; mt < 4; mt++) {
            float4 b1v = *reinterpret_cast<const float4*>(&b1[nc * 128 + whid + mt * 16 + quad * 4]);
            const float* b1p = reinterpret_cast<const float*>(&b1v);
#pragma unroll
            for (int nt = 0; nt < 2; nt++) {
                bf16x4 h4;
#pragma unroll
                for (int r = 0; r < 4; r++) {
                    float v = gelu_fast(sT[mt][nt][r] + b1p[r]);
                    tsum[nt] += v;
                    tss[nt] = fmaf(v, v, tss[nt]);
                    h4[r] = (bf16)v;
                }
                int tok  = wtok1 + nt * 16 + l16;          // tok&7 == l16&7
                int hidb = (whid + mt * 16 + quad * 4) ^ swzr;
                *reinterpret_cast<bf16x4*>(&lH[tok * 128 + hidb]) = h4;
            }
        }
        __syncthreads();   // lH visible; lP free
        // ---- phase B: U += Hc @ W2g chunk ----
#pragma unroll
        for (int k2s = 0; k2s < 2; k2s++) {
#pragma unroll
            for (int j = 0; j < 8; j++)
                gload_lds16(W2t + (size_t)(w * 64 + j * 8 + lrow) * 1024
                                + nc * 128 + k2s * 64 + scol,
                            &lW2[(w * 64 + j * 8) * 64]);
            __syncthreads();
#pragma unroll
            for (int ks2 = 0; ks2 < 64; ks2 += 32) {
                bf16x8 hf[2];
#pragma unroll
                for (int i = 0; i < 2; i++)
                    hf[i] = *reinterpret_cast<const bf16x8*>(
                        &lH[(wtok2 + i * 16 + l16) * 128 + ((k2s * 64 + ks2 + quad * 8) ^ swzr)]);
#pragma unroll
                for (int g4 = 0; g4 < 2; g4++) {           // 2 passes of 4 B-frags
                    bf16x8 vf[4];
#pragma unroll
                    for (int i = 0; i < 4; i++)
                        vf[i] = *reinterpret_cast<const bf16x8*>(
                            &lW2[(wout + (g4 * 4 + i) * 16 + l16) * 64 + ((ks2 + quad * 8) ^ swzr)]);
#pragma unroll
                    for (int mi = 0; mi < 2; mi++)
#pragma unroll
                        for (int i = 0; i < 4; i++)
                            acc2[mi][g4 * 4 + i] = __builtin_amdgcn_mfma_f32_16x16x32_bf16(
                                hf[mi], vf[i], acc2[mi][g4 * 4 + i], 0, 0, 0);
                }
            }
            __syncthreads();
        }
    }

    // ---- cross-wave stats combine (hid halves live in waves w and w^2) ----
    // lstats aliases lP: safe — last phase B ended with a barrier, lP dead.
#pragma unroll
    for (int nt = 0; nt < 2; nt++) {
        float s = tsum[nt], ss = tss[nt];
        s  += __shfl_xor(s, 16, 64);  ss += __shfl_xor(ss, 16, 64);
        s  += __shfl_xor(s, 32, 64);  ss += __shfl_xor(ss, 32, 64);
        if (quad == 0) lstats[(wtok1 + nt * 16 + l16) * 2 + (w >> 1)] = make_float2(s, ss);
    }
    __syncthreads();

    // ---- epilogue: out = rstd*U + (-mean*rstd)*c2 + c1 + b2 + resid ----
    float bcol[8]; float2 cc[8];
#pragma unroll
    for (int ni = 0; ni < 8; ni++) {
        int col = wout + ni * 16 + l16;
        bcol[ni] = b2[col];
        cc[ni] = c12[col];
    }
#pragma unroll
    for (int mi = 0; mi < 2; mi++) {
#pragma unroll
        for (int r = 0; r < 4; r++) {
            int rl = wtok2 + mi * 16 + quad * 4 + r;
            float2 p0 = lstats[rl * 2 + 0], p1 = lstats[rl * 2 + 1];
            float s = p0.x + p1.x, ss = p0.y + p1.y;
            float mean = s * (1.0f / HIDD);
            float var  = ss * (1.0f / HIDD) - mean * mean;
            if (var < 0.f) var = 0.f;
            float rstd = rsqrtf(var + 1e-5f);
            float ofs = -mean * rstd;
            size_t row = m0 + rl;
            const float* rr = resid + row * CDIM;
            float* orow = out + row * CDIM;
#pragma unroll
            for (int ni = 0; ni < 8; ni++) {
                int col = wout + ni * 16 + l16;
                float v = fmaf(rstd, acc2[mi][ni][r], fmaf(ofs, cc[ni].y, cc[ni].x + bcol[ni]));
                orow[col] = v + rr[col];
            }
        }
    }
}

// ---------------- windowed attention, one wave = one (batch, window, head) ----------------
__global__ __launch_bounds__(256) void attn_kernel(
    const bf16* __restrict__ qkv, const float* __restrict__ X,
    float* __restrict__ x1)
{
    __shared__ bf16 pbuf[4][64 * 72];
    __shared__ bf16 vtbuf[4][32 * 72];
    const int w = threadIdx.x >> 6, lane = threadIdx.x & 63;
    const int quad = lane >> 4, l16 = lane & 15;
    const int blk = blockIdx.x;
    const int hg = blk & 1, p = (blk >> 1) & 63, b = blk >> 7;
    const int h = hg * 4 + w;
    const int py = p >> 3, px = p & 7;
    const size_t gbase = (size_t)b * NTOK + py * 7 * 56 + px * 7;
    bf16* P  = pbuf[w];
    bf16* VT = vtbuf[w];

    unsigned int* vz = (unsigned int*)VT;
    for (int i = lane; i < 32 * 72 / 2; i += 64) vz[i] = 0u;

    for (int idx = lane; idx < 49 * 4; idx += 64) {
        int tk = idx >> 2, d8 = (idx & 3) * 8;
        size_t g = gbase + (tk / 7) * 56 + (tk % 7);
        bf16x8 vv = *reinterpret_cast<const bf16x8*>(qkv + g * 768 + 512 + h * 32 + d8);
#pragma unroll
        for (int j = 0; j < 8; j++) VT[(d8 + j) * 72 + tk] = vv[j];
    }

    bf16x8 qf[4], kf[4];
#pragma unroll
    for (int mt = 0; mt < 4; mt++) {
        int i = mt * 16 + l16; if (i > 48) i = 48;
        size_t g = gbase + (i / 7) * 56 + (i % 7);
        qf[mt] = *reinterpret_cast<const bf16x8*>(qkv + g * 768 +       h * 32 + quad * 8);
        kf[mt] = *reinterpret_cast<const bf16x8*>(qkv + g * 768 + 256 + h * 32 + quad * 8);
    }

    floatx4 s[4][4];
#pragma unroll
    for (int mt = 0; mt < 4; mt++)
#pragma unroll
        for (int nt = 0; nt < 4; nt++) {
            floatx4 z = {};
            s[mt][nt] = __builtin_amdgcn_mfma_f32_16x16x32_bf16(qf[mt], kf[nt], z, 0, 0, 0);
        }

#pragma unroll
    for (int mt = 0; mt < 4; mt++) {
#pragma unroll
        for (int r = 0; r < 4; r++) {
            float mx = -1e30f;
#pragma unroll
            for (int nt = 0; nt < 4; nt++) {
                int col = nt * 16 + l16;
                float v = (col < 49) ? s[mt][nt][r] * ATTN_SCALE : -1e30f;
                s[mt][nt][r] = v;
                mx = fmaxf(mx, v);
            }
#pragma unroll
            for (int off = 1; off < 16; off <<= 1) mx = fmaxf(mx, __shfl_xor(mx, off, 64));
            float sum = 0.f;
#pragma unroll
            for (int nt = 0; nt < 4; nt++) {
                float e = __expf(s[mt][nt][r] - mx);
                s[mt][nt][r] = e;
                sum += e;
            }
#pragma unroll
            for (int off = 1; off < 16; off <<= 1) sum += __shfl_xor(sum, off, 64);
            float inv = 1.0f / sum;
            int prow = mt * 16 + quad * 4 + r;
#pragma unroll
            for (int nt = 0; nt < 4; nt++)
                P[prow * 72 + nt * 16 + l16] = (bf16)(s[mt][nt][r] * inv);
        }
    }

    __syncthreads();

    floatx4 o[4][2] = {};
#pragma unroll
    for (int ks = 0; ks < 2; ks++) {
        bf16x8 pf[4], vf[2];
#pragma unroll
        for (int mt = 0; mt < 4; mt++)
            pf[mt] = *reinterpret_cast<const bf16x8*>(&P[(mt * 16 + l16) * 72 + ks * 32 + quad * 8]);
#pragma unroll
        for (int nt = 0; nt < 2; nt++)
            vf[nt] = *reinterpret_cast<const bf16x8*>(&VT[(nt * 16 + l16) * 72 + ks * 32 + quad * 8]);
#pragma unroll
        for (int mt = 0; mt < 4; mt++)
#pragma unroll
            for (int nt = 0; nt < 2; nt++)
                o[mt][nt] = __builtin_amdgcn_mfma_f32_16x16x32_bf16(pf[mt], vf[nt], o[mt][nt], 0, 0, 0);
    }

#pragma unroll
    for (int mt = 0; mt < 4; mt++) {
#pragma unroll
        for (int r = 0; r < 4; r++) {
            int i = mt * 16 + quad * 4 + r;
            if (i < 49) {
                size_t g = gbase + (i / 7) * 56 + (i % 7);
#pragma unroll
                for (int nt = 0; nt < 2; nt++) {
                    size_t adr = g * CDIM + h * 32 + nt * 16 + l16;
                    x1[adr] = X[adr] + o[mt][nt][r];
                }
            }
        }
    }
}

// ---------------- launcher ----------------
// Base layout (proven): qkv_wt | fc1_wt | fc2_wt | xn | union(qkvb, hbuf) = 258,342,912 B.
// Tail (fused path, 34,816 B): c12p[16*256] f2 | c12[256] f2.
extern "C" void kernel_launch(void* const* d_in, const int* in_sizes, int n_in,
                              void* d_out, int out_size, void* d_ws, size_t ws_size,
                              hipStream_t stream) {
    const float* x      = (const float*)d_in[0];
    const float* ln1_g  = (const float*)d_in[1];
    const float* ln1_b  = (const float*)d_in[2];
    const float* qkv_w  = (const float*)d_in[3];
    const float* qkv_b  = (const float*)d_in[4];
    const float* ln2_g  = (const float*)d_in[5];
    const float* ln2_b  = (const float*)d_in[6];
    const float* fc1_w  = (const float*)d_in[7];
    const float* fc1_b  = (const float*)d_in[8];
    const float* mlp_g  = (const float*)d_in[9];
    const float* mlp_b  = (const float*)d_in[10];
    const float* fc2_w  = (const float*)d_in[11];
    const float* fc2_b  = (const float*)d_in[12];
    float* out = (float*)d_out;

    char* ws = (char*)d_ws;
    bf16* qkv_wt = (bf16*)ws;  ws += (size_t)768 * 256 * 2;
    bf16* fc1_wt = (bf16*)ws;  ws += (size_t)1024 * 256 * 2;
    bf16* fc2_wt = (bf16*)ws;  ws += (size_t)256 * 1024 * 2;
    bf16* xn     = (bf16*)ws;  ws += (size_t)MROWS * CDIM * 2;   // reused as x1n
    bf16* qkvb   = (bf16*)ws;                                     // union with hbuf
    bf16* hbuf   = (bf16*)ws;  ws += (size_t)MROWS * HIDD * 2;

    const size_t base_bytes = (size_t)(ws - (char*)d_ws);
    const size_t tail_bytes = (size_t)16 * 256 * sizeof(float2) + (size_t)256 * sizeof(float2);
    const bool fuse = (ws_size >= base_bytes + tail_bytes);
    const int swz = fuse ? 0x38 : 0;

    float2* c12p = (float2*)ws;
    float2* c12  = c12p + 16 * 256;
    float* x1 = out;

    // weight prep (pre-swizzled on the fused path)
    wt_kernel<<<768,  256, 0, stream>>>(qkv_w, qkv_wt, 256, 768, nullptr, swz);
    wt_kernel<<<1024, 256, 0, stream>>>(fc1_w, fc1_wt, 256, 1024, nullptr, swz);
    wt_kernel<<<1024, 256, 0, stream>>>(fc2_w, fc2_wt, 1024, 256,
                                        fuse ? mlp_g : nullptr, swz);
    if (fuse) {
        c12_part_kernel<<<16, 256, 0, stream>>>(fc2_w, mlp_g, mlp_b, c12p);
        c12_red_kernel<<<1, 256, 0, stream>>>(c12p, c12);
    }

    ln_apply_f32_kernel<<<MROWS / 4, 256, 0, stream>>>(x, ln1_g, ln1_b, xn, swz);
    if (fuse)
        gemm_bt_kernel<0, true, bf16><<<dim3(768 / 128, MROWS / 128), 256, 0, stream>>>(
            xn, qkv_wt, qkv_b, nullptr, qkvb, 768, 256);
    else
        gemm_bt_kernel<0, false, bf16><<<dim3(768 / 128, MROWS / 128), 256, 0, stream>>>(
            xn, qkv_wt, qkv_b, nullptr, qkvb, 768, 256);
    attn_kernel<<<BATCH * 64 * 2, 256, 0, stream>>>(qkvb, x, x1);
    ln_apply_f32_kernel<<<MROWS / 4, 256, 0, stream>>>(x1, ln2_g, ln2_b, xn, swz);

    if (fuse) {
        mlp_fused_kernel<<<MROWS / 64, 256, 0, stream>>>(
            xn, fc1_wt, fc2_wt, fc1_b, fc2_b, x1, c12, out);
    } else {
        gemm_bt_kernel<1, false, bf16><<<dim3(HIDD / 128, MROWS / 128), 256, 0, stream>>>(
            xn, fc1_wt, fc1_b, nullptr, hbuf, HIDD, 256);
        ln_inplace_h_kernel<<<MROWS / 4, 256, 0, stream>>>(hbuf, mlp_g, mlp_b);
        gemm_bt_kernel<3, false, float><<<dim3(CDIM / 128, MROWS / 128), 256, 0, stream>>>(
            hbuf, fc2_wt, fc2_b, x1, out, CDIM, 1024);
    }
}

// Round 14
// 628.864 us; speedup vs baseline: 1.1791x; 1.1791x over previous
//
#include <hip/hip_runtime.h>
#include <cmath>

// ---- TwinsBlock: B=32, H=W=56, C=256, heads=8, ws=7. fp32 I/O, bf16 MFMA ----
// R14: R13 with ONE change — __launch_bounds__(256, 2) on mlp_fused.
// R13's (256,3) drove hipcc's VGPR cap to 84 (~512/6; empirical cap table:
// (512,4)->64, (512,2)->92<=128, (256,2)->100<=256, (256,3)->84), spilling
// the ~166-VGPR xreg working set (FETCH 484MB/WRITE 383MB scratch, 358us).
// With (256,2) the cap is >=256; allocation ~166 -> runtime occupancy
// self-limits at floor(512/166)=3 waves/SIMD = 3 blocks/CU = the 12-wave
// TLP target. xreg design kept (R13 passed; LDS 48KB, no phase-A ds_reads).
// All other kernels identical to R13 (passing).
typedef __bf16 bf16;
typedef __bf16 bf16x4 __attribute__((ext_vector_type(4)));
typedef __bf16 bf16x8 __attribute__((ext_vector_type(8)));
typedef float floatx4 __attribute__((ext_vector_type(4)));

constexpr int BATCH = 32;
constexpr int NTOK  = 3136;            // 56*56
constexpr int CDIM  = 256;
constexpr int MROWS = BATCH * NTOK;    // 100352
constexpr int HIDD  = 1024;
constexpr float ATTN_SCALE = 0.17677669529663689f;  // 32^-0.5

// tanh-form GELU: x * sigmoid(1.5957691*(x + 0.044715 x^3)).
__device__ __forceinline__ float gelu_fast(float x) {
    float p = fmaf(0.044715f * x, x * x, x);
    return __fdividef(x, 1.0f + __expf(-1.5957691216057308f * p));
}

__device__ __forceinline__ void load8(const bf16* p, float* o) {
    bf16x8 v = *reinterpret_cast<const bf16x8*>(p);
#pragma unroll
    for (int j = 0; j < 8; j++) o[j] = (float)v[j];
}

// async global->LDS, 16B per lane, wave-uniform LDS base + lane*16
__device__ __forceinline__ void gload_lds16(const void* g, void* l) {
    __builtin_amdgcn_global_load_lds(
        (const __attribute__((address_space(1))) void*)g,
        (__attribute__((address_space(3))) void*)l, 16, 0, 0);
}

// ---------------- weight convert + transpose: fp32 [K,N] -> bf16 [N,K] ----------------
// gsc: fold mlp_ln_g into fc2 rows. swz: pre-swizzle k by ((n&7)<<3) (8-elem granule).
__global__ __launch_bounds__(256) void wt_kernel(
    const float* __restrict__ Win, bf16* __restrict__ Wt, int Ksz, int Nsz,
    const float* __restrict__ gsc, int swz)
{
    int id = blockIdx.x * 256 + threadIdx.x;
    int n = id / Ksz, k = id % Ksz;
    float v = Win[(size_t)k * Nsz + n];
    if (gsc) v *= gsc[k];
    int kp = k ^ (swz & ((n & 7) << 3));
    Wt[(size_t)n * Ksz + kp] = (bf16)v;
}

// ---------------- c1/c2 column corrections for folded mlp-LN ----------------
__global__ __launch_bounds__(256) void c12_part_kernel(
    const float* __restrict__ W, const float* __restrict__ g,
    const float* __restrict__ b, float2* __restrict__ part)   // part[16][256]
{
    int n = threadIdx.x, j = blockIdx.x;
    float c1 = 0.f, c2 = 0.f;
#pragma unroll 8
    for (int k = j * 64; k < j * 64 + 64; k++) {
        float w = W[(size_t)k * 256 + n];
        c1 = fmaf(b[k], w, c1);
        c2 = fmaf(g[k], w, c2);
    }
    part[j * 256 + n] = make_float2(c1, c2);
}

__global__ __launch_bounds__(256) void c12_red_kernel(
    const float2* __restrict__ part, float2* __restrict__ c12)
{
    int n = threadIdx.x;
    float c1 = 0.f, c2 = 0.f;
#pragma unroll
    for (int j = 0; j < 16; j++) { float2 p = part[j * 256 + n]; c1 += p.x; c2 += p.y; }
    c12[n] = make_float2(c1, c2);
}

// ---------------- fused LN (stats+apply): fp32 [M,256] -> bf16 [M,256] ----------------
// swz: pre-swizzle output cols by ((tok&7)<<3) so GEMM ds_reads are conflict-free.
__global__ __launch_bounds__(256) void ln_apply_f32_kernel(
    const float* __restrict__ X, const float* __restrict__ g,
    const float* __restrict__ b, bf16* __restrict__ Y, int swz)
{
    int tok  = (blockIdx.x * 256 + threadIdx.x) >> 6;   // one wave per token
    int lane = threadIdx.x & 63;
    const float* row = X + (size_t)tok * CDIM;
    float4 v = *reinterpret_cast<const float4*>(row + lane * 4);
    float s  = v.x + v.y + v.z + v.w;
    float ss = v.x * v.x + v.y * v.y + v.z * v.z + v.w * v.w;
#pragma unroll
    for (int off = 32; off > 0; off >>= 1) {
        s  += __shfl_xor(s,  off, 64);
        ss += __shfl_xor(ss, off, 64);
    }
    float mean = s * (1.0f / CDIM);
    float var  = ss * (1.0f / CDIM) - mean * mean;
    if (var < 0.f) var = 0.f;
    float rstd = rsqrtf(var + 1e-5f);
    float4 gg = *reinterpret_cast<const float4*>(g + lane * 4);
    float4 bb = *reinterpret_cast<const float4*>(b + lane * 4);
    bf16x4 o;
    o[0] = (bf16)((v.x - mean) * rstd * gg.x + bb.x);
    o[1] = (bf16)((v.y - mean) * rstd * gg.y + bb.y);
    o[2] = (bf16)((v.z - mean) * rstd * gg.z + bb.z);
    o[3] = (bf16)((v.w - mean) * rstd * gg.w + bb.w);
    int off4 = (lane * 4) ^ (swz & ((tok & 7) << 3));   // 4-granule preserved
    *reinterpret_cast<bf16x4*>(Y + (size_t)tok * CDIM + off4) = o;
}

// ---------------- fallback: fused LN in-place over bf16 [M,1024] ----------------
__global__ __launch_bounds__(256) void ln_inplace_h_kernel(
    bf16* __restrict__ H, const float* __restrict__ g, const float* __restrict__ b)
{
    int tok  = (blockIdx.x * 256 + threadIdx.x) >> 6;
    int lane = threadIdx.x & 63;
    bf16* row = H + (size_t)tok * HIDD;
    float f[16];
    load8(row + lane * 8, f);
    load8(row + 512 + lane * 8, f + 8);
    float s = 0.f, ss = 0.f;
#pragma unroll
    for (int j = 0; j < 16; j++) { s += f[j]; ss += f[j] * f[j]; }
#pragma unroll
    for (int off = 32; off > 0; off >>= 1) {
        s  += __shfl_xor(s,  off, 64);
        ss += __shfl_xor(ss, off, 64);
    }
    float mean = s * (1.0f / HIDD);
    float var  = ss * (1.0f / HIDD) - mean * mean;
    if (var < 0.f) var = 0.f;
    float rstd = rsqrtf(var + 1e-5f);
    bf16x8 o0, o1;
#pragma unroll
    for (int j = 0; j < 8; j++) {
        o0[j] = (bf16)((f[j]     - mean) * rstd * g[lane * 8 + j]       + b[lane * 8 + j]);
        o1[j] = (bf16)((f[j + 8] - mean) * rstd * g[512 + lane * 8 + j] + b[512 + lane * 8 + j]);
    }
    *reinterpret_cast<bf16x8*>(row + lane * 8) = o0;
    *reinterpret_cast<bf16x8*>(row + 512 + lane * 8) = o1;
}

// ---------------- m97-style GEMM: out = epi( A[M,K] @ Bt[N,K]^T + bias ) ----------------
// EPI 0: bias. EPI 1: bias+GELU. EPI 3: bias+resid.
// SWZ: A/Bt are pre-swizzled (8-elem granule by row&7) -> XOR on fragment reads.
template<int EPI, bool SWZ, typename TO>
__global__ __launch_bounds__(256) void gemm_bt_kernel(
    const bf16* __restrict__ A, const bf16* __restrict__ Bt,
    const float* __restrict__ bias, const float* __restrict__ resid,
    TO* __restrict__ out, int Nsz, int Ksz)
{
    __shared__ bf16 lA[128 * 64];
    __shared__ bf16 lB[128 * 64];
    const int t = threadIdx.x;
    const int lane = t & 63, w = t >> 6;
    const int quad = lane >> 4, l16 = lane & 15;
    const int wm = (w >> 1) * 64, wn = (w & 1) * 64;

    const int gx   = gridDim.x;
    const int flat = blockIdx.y * gx + blockIdx.x;
    const int cpx  = (gx * gridDim.y) >> 3;
    const int fl2  = (flat & 7) * cpx + (flat >> 3);   // bijective (nwg%8==0)
    const int bx   = fl2 % gx, by = fl2 / gx;

    const size_t m0 = (size_t)by * 128;
    const int n0 = bx * 128;
    const int srow = w * 32 + (lane >> 3);
    const int scol = (lane & 7) * 8;
    const int swzr = SWZ ? ((l16 & 7) << 3) : 0;   // frag-row&7 == l16&7

    floatx4 acc[4][4] = {};

    for (int kc = 0; kc < Ksz; kc += 64) {
#pragma unroll
        for (int j = 0; j < 4; j++) {
            gload_lds16(A  + (m0 + srow + j * 8) * Ksz + kc + scol, &lA[(w * 32 + j * 8) * 64]);
            gload_lds16(Bt + (size_t)(n0 + srow + j * 8) * Ksz + kc + scol, &lB[(w * 32 + j * 8) * 64]);
        }
        __syncthreads();
#pragma unroll
        for (int ks = 0; ks < 64; ks += 32) {
            bf16x8 af[4], bfv[4];
#pragma unroll
            for (int i = 0; i < 4; i++) {
                af[i]  = *reinterpret_cast<const bf16x8*>(&lA[(wm + i * 16 + l16) * 64 + ((ks + quad * 8) ^ swzr)]);
                bfv[i] = *reinterpret_cast<const bf16x8*>(&lB[(wn + i * 16 + l16) * 64 + ((ks + quad * 8) ^ swzr)]);
            }
#pragma unroll
            for (int mi = 0; mi < 4; mi++)
#pragma unroll
                for (int ni = 0; ni < 4; ni++)
                    acc[mi][ni] = __builtin_amdgcn_mfma_f32_16x16x32_bf16(af[mi], bfv[ni], acc[mi][ni], 0, 0, 0);
        }
        __syncthreads();
    }

#pragma unroll
    for (int mi = 0; mi < 4; mi++) {
#pragma unroll
        for (int ni = 0; ni < 4; ni++) {
            int col = n0 + wn + ni * 16 + l16;
            float bcol = bias[col];
#pragma unroll
            for (int r = 0; r < 4; r++) {
                size_t row = m0 + wm + mi * 16 + quad * 4 + r;
                float v = acc[mi][ni][r] + bcol;
                if (EPI == 1) v = gelu_fast(v);
                if (EPI == 3) v += resid[row * (size_t)Nsz + col];
                out[row * (size_t)Nsz + col] = (TO)v;
            }
        }
    }
}

// ---------------- fused MLP: out = resid + LN(gelu(xn@W1+b1))@W2g + b2 ----------------
// 64-row tile, 4 waves. X fragments preloaded to REGISTERS (32 VGPR/lane,
// from pre-swizzled xn). Per nc (8 chunks of 128 hid):
//   phase A: 2 x {stage lW1[128][128], barrier, 4 ks x 8 MFMA (xf from regs), barrier}
//   gelu+stats in regs -> bf16x4 -> XOR-swizzled lH[64][128]; barrier
//   phase B: 2 x {stage lW2[256][64], barrier, 32 MFMA, barrier}
// LDS 48KB (lP 32 + lH 16, lstats aliases lP); VGPR ~166 -> 3 blocks/CU at runtime.
__global__ __launch_bounds__(256, 2) void mlp_fused_kernel(
    const bf16* __restrict__ A,      // xn [M][256], pre-swizzled
    const bf16* __restrict__ W1t,    // [1024][256], pre-swizzled
    const bf16* __restrict__ W2t,    // [256][1024], pre-swizzled, g-folded
    const float* __restrict__ b1, const float* __restrict__ b2,
    const float* __restrict__ resid, const float2* __restrict__ c12,
    float* __restrict__ out)
{
    __shared__ bf16 lP[16384];          // 32KB: lW1[128][128] | lW2[256][64] | lstats
    __shared__ bf16 lH[64 * 128];       // 16KB, [tok][hid] XOR-swizzled

    const int t = threadIdx.x;
    const int lane = t & 63, w = t >> 6;
    const int quad = lane >> 4, l16 = lane & 15;
    const int whid  = (w >> 1) * 64, wtok1 = (w & 1) * 32;   // GEMM1 roles
    const int wtok2 = (w >> 1) * 32, wout  = (w & 1) * 128;  // GEMM2 roles

    const int cpx = gridDim.x >> 3;            // 1568/8 = 196
    const int bid = (blockIdx.x & 7) * cpx + (blockIdx.x >> 3);
    const size_t m0 = (size_t)bid * 64;

    const int srow = t >> 4;                   // 0..15 (lW1 staging, 16 lanes/row)
    const int schk = (t & 15) * 8;
    const int lrow = lane >> 3;                // lW2 staging: 8 lanes/row
    const int scol = (lane & 7) * 8;
    const int swzr = (l16 & 7) << 3;

    bf16* lW1 = lP;                            // [128][128]
    bf16* lW2 = lP;                            // [256][64]
    float2* lstats = (float2*)lP;              // [64][2], epilogue only

    // ---- preload X fragments to registers: xreg[tok-grp][k8] (32 VGPR) ----
    // logical (tok, col k8*32+quad*8 .. +8); xn pre-swizzled by (tok&7)*8,
    // tok == l16 (mod 8) so XOR key = swzr. 16 x 16B loads per lane.
    bf16x8 xreg[2][8];
#pragma unroll
    for (int i = 0; i < 2; i++) {
        const bf16* xrow = A + (m0 + wtok1 + i * 16 + l16) * 256;
#pragma unroll
        for (int k8 = 0; k8 < 8; k8++)
            xreg[i][k8] = *reinterpret_cast<const bf16x8*>(
                xrow + ((k8 * 32 + quad * 8) ^ swzr));
    }

    floatx4 acc2[2][8] = {};                   // U: [tok-mi][out-ni]
    float tsum[2] = {0.f, 0.f};
    float tss[2]  = {0.f, 0.f};

    for (int nc = 0; nc < 8; nc++) {
        // ---- phase A: Hc^T = (xn @ W1 chunk)^T, two K=128 sub-chunks ----
        floatx4 sT[4][2] = {};                 // [hid-mt][tok-nt]
#pragma unroll
        for (int kc2 = 0; kc2 < 2; kc2++) {
            const int kc = kc2 * 128;
#pragma unroll
            for (int j = 0; j < 8; j++)        // lW1: 128 rows x 128 cols
                gload_lds16(W1t + (size_t)(nc * 128 + j * 16 + srow) * 256 + kc + schk,
                            &lW1[(j * 16 + w * 4) * 128]);
            __syncthreads();
#pragma unroll
            for (int ksi = 0; ksi < 4; ksi++) {
                const int ks = ksi * 32;
                bf16x8 wf[4];
#pragma unroll
                for (int i = 0; i < 4; i++)
                    wf[i] = *reinterpret_cast<const bf16x8*>(
                        &lW1[(whid + i * 16 + l16) * 128 + ((ks + quad * 8) ^ swzr)]);
#pragma unroll
                for (int mt = 0; mt < 4; mt++)
#pragma unroll
                    for (int nt = 0; nt < 2; nt++)
                        sT[mt][nt] = __builtin_amdgcn_mfma_f32_16x16x32_bf16(
                            wf[mt], xreg[nt][kc2 * 4 + ksi], sT[mt][nt], 0, 0, 0);
            }
            __syncthreads();
        }
        // ---- bias + gelu + stats + pack -> lH[tok][hid^swz] ----
#pragma unroll
        for (int mt = 0; mt < 4; mt++) {
            float4 b1v = *reinterpret_cast<const float4*>(&b1[nc * 128 + whid + mt * 16 + quad * 4]);
            const float* b1p = reinterpret_cast<const float*>(&b1v);
#pragma unroll
            for (int nt = 0; nt < 2; nt++) {
                bf16x4 h4;
#pragma unroll
                for (int r = 0; r < 4; r++) {
                    float v = gelu_fast(sT[mt][nt][r] + b1p[r]);
                    tsum[nt] += v;
                    tss[nt] = fmaf(v, v, tss[nt]);
                    h4[r] = (bf16)v;
                }
                int tok  = wtok1 + nt * 16 + l16;          // tok&7 == l16&7
                int hidb = (whid + mt * 16 + quad * 4) ^ swzr;
                *reinterpret_cast<bf16x4*>(&lH[tok * 128 + hidb]) = h4;
            }
        }
        __syncthreads();   // lH visible; lP free
        // ---- phase B: U += Hc @ W2g chunk ----
#pragma unroll
        for (int k2s = 0; k2s < 2; k2s++) {
#pragma unroll
            for (int j = 0; j < 8; j++)
                gload_lds16(W2t + (size_t)(w * 64 + j * 8 + lrow) * 1024
                                + nc * 128 + k2s * 64 + scol,
                            &lW2[(w * 64 + j * 8) * 64]);
            __syncthreads();
#pragma unroll
            for (int ks2 = 0; ks2 < 64; ks2 += 32) {
                bf16x8 hf[2];
#pragma unroll
                for (int i = 0; i < 2; i++)
                    hf[i] = *reinterpret_cast<const bf16x8*>(
                        &lH[(wtok2 + i * 16 + l16) * 128 + ((k2s * 64 + ks2 + quad * 8) ^ swzr)]);
#pragma unroll
                for (int g4 = 0; g4 < 2; g4++) {           // 2 passes of 4 B-frags
                    bf16x8 vf[4];
#pragma unroll
                    for (int i = 0; i < 4; i++)
                        vf[i] = *reinterpret_cast<const bf16x8*>(
                            &lW2[(wout + (g4 * 4 + i) * 16 + l16) * 64 + ((ks2 + quad * 8) ^ swzr)]);
#pragma unroll
                    for (int mi = 0; mi < 2; mi++)
#pragma unroll
                        for (int i = 0; i < 4; i++)
                            acc2[mi][g4 * 4 + i] = __builtin_amdgcn_mfma_f32_16x16x32_bf16(
                                hf[mi], vf[i], acc2[mi][g4 * 4 + i], 0, 0, 0);
                }
            }
            __syncthreads();
        }
    }

    // ---- cross-wave stats combine (hid halves live in waves w and w^2) ----
    // lstats aliases lP: safe — last phase B ended with a barrier, lP dead.
#pragma unroll
    for (int nt = 0; nt < 2; nt++) {
        float s = tsum[nt], ss = tss[nt];
        s  += __shfl_xor(s, 16, 64);  ss += __shfl_xor(ss, 16, 64);
        s  += __shfl_xor(s, 32, 64);  ss += __shfl_xor(ss, 32, 64);
        if (quad == 0) lstats[(wtok1 + nt * 16 + l16) * 2 + (w >> 1)] = make_float2(s, ss);
    }
    __syncthreads();

    // ---- epilogue: out = rstd*U + (-mean*rstd)*c2 + c1 + b2 + resid ----
    float bcol[8]; float2 cc[8];
#pragma unroll
    for (int ni = 0; ni < 8; ni++) {
        int col = wout + ni * 16 + l16;
        bcol[ni] = b2[col];
        cc[ni] = c12[col];
    }
#pragma unroll
    for (int mi = 0; mi < 2; mi++) {
#pragma unroll
        for (int r = 0; r < 4; r++) {
            int rl = wtok2 + mi * 16 + quad * 4 + r;
            float2 p0 = lstats[rl * 2 + 0], p1 = lstats[rl * 2 + 1];
            float s = p0.x + p1.x, ss = p0.y + p1.y;
            float mean = s * (1.0f / HIDD);
            float var  = ss * (1.0f / HIDD) - mean * mean;
            if (var < 0.f) var = 0.f;
            float rstd = rsqrtf(var + 1e-5f);
            float ofs = -mean * rstd;
            size_t row = m0 + rl;
            const float* rr = resid + row * CDIM;
            float* orow = out + row * CDIM;
#pragma unroll
            for (int ni = 0; ni < 8; ni++) {
                int col = wout + ni * 16 + l16;
                float v = fmaf(rstd, acc2[mi][ni][r], fmaf(ofs, cc[ni].y, cc[ni].x + bcol[ni]));
                orow[col] = v + rr[col];
            }
        }
    }
}

// ---------------- windowed attention, one wave = one (batch, window, head) ----------------
__global__ __launch_bounds__(256) void attn_kernel(
    const bf16* __restrict__ qkv, const float* __restrict__ X,
    float* __restrict__ x1)
{
    __shared__ bf16 pbuf[4][64 * 72];
    __shared__ bf16 vtbuf[4][32 * 72];
    const int w = threadIdx.x >> 6, lane = threadIdx.x & 63;
    const int quad = lane >> 4, l16 = lane & 15;
    const int blk = blockIdx.x;
    const int hg = blk & 1, p = (blk >> 1) & 63, b = blk >> 7;
    const int h = hg * 4 + w;
    const int py = p >> 3, px = p & 7;
    const size_t gbase = (size_t)b * NTOK + py * 7 * 56 + px * 7;
    bf16* P  = pbuf[w];
    bf16* VT = vtbuf[w];

    unsigned int* vz = (unsigned int*)VT;
    for (int i = lane; i < 32 * 72 / 2; i += 64) vz[i] = 0u;

    for (int idx = lane; idx < 49 * 4; idx += 64) {
        int tk = idx >> 2, d8 = (idx & 3) * 8;
        size_t g = gbase + (tk / 7) * 56 + (tk % 7);
        bf16x8 vv = *reinterpret_cast<const bf16x8*>(qkv + g * 768 + 512 + h * 32 + d8);
#pragma unroll
        for (int j = 0; j < 8; j++) VT[(d8 + j) * 72 + tk] = vv[j];
    }

    bf16x8 qf[4], kf[4];
#pragma unroll
    for (int mt = 0; mt < 4; mt++) {
        int i = mt * 16 + l16; if (i > 48) i = 48;
        size_t g = gbase + (i / 7) * 56 + (i % 7);
        qf[mt] = *reinterpret_cast<const bf16x8*>(qkv + g * 768 +       h * 32 + quad * 8);
        kf[mt] = *reinterpret_cast<const bf16x8*>(qkv + g * 768 + 256 + h * 32 + quad * 8);
    }

    floatx4 s[4][4];
#pragma unroll
    for (int mt = 0; mt < 4; mt++)
#pragma unroll
        for (int nt = 0; nt < 4; nt++) {
            floatx4 z = {};
            s[mt][nt] = __builtin_amdgcn_mfma_f32_16x16x32_bf16(qf[mt], kf[nt], z, 0, 0, 0);
        }

#pragma unroll
    for (int mt = 0; mt < 4; mt++) {
#pragma unroll
        for (int r = 0; r < 4; r++) {
            float mx = -1e30f;
#pragma unroll
            for (int nt = 0; nt < 4; nt++) {
                int col = nt * 16 + l16;
                float v = (col < 49) ? s[mt][nt][r] * ATTN_SCALE : -1e30f;
                s[mt][nt][r] = v;
                mx = fmaxf(mx, v);
            }
#pragma unroll
            for (int off = 1; off < 16; off <<= 1) mx = fmaxf(mx, __shfl_xor(mx, off, 64));
            float sum = 0.f;
#pragma unroll
            for (int nt = 0; nt < 4; nt++) {
                float e = __expf(s[mt][nt][r] - mx);
                s[mt][nt][r] = e;
                sum += e;
            }
#pragma unroll
            for (int off = 1; off < 16; off <<= 1) sum += __shfl_xor(sum, off, 64);
            float inv = 1.0f / sum;
            int prow = mt * 16 + quad * 4 + r;
#pragma unroll
            for (int nt = 0; nt < 4; nt++)
                P[prow * 72 + nt * 16 + l16] = (bf16)(s[mt][nt][r] * inv);
        }
    }

    __syncthreads();

    floatx4 o[4][2] = {};
#pragma unroll
    for (int ks = 0; ks < 2; ks++) {
        bf16x8 pf[4], vf[2];
#pragma unroll
        for (int mt = 0; mt < 4; mt++)
            pf[mt] = *reinterpret_cast<const bf16x8*>(&P[(mt * 16 + l16) * 72 + ks * 32 + quad * 8]);
#pragma unroll
        for (int nt = 0; nt < 2; nt++)
            vf[nt] = *reinterpret_cast<const bf16x8*>(&VT[(nt * 16 + l16) * 72 + ks * 32 + quad * 8]);
#pragma unroll
        for (int mt = 0; mt < 4; mt++)
#pragma unroll
            for (int nt = 0; nt < 2; nt++)
                o[mt][nt] = __builtin_amdgcn_mfma_f32_16x16x32_bf16(pf[mt], vf[nt], o[mt][nt], 0, 0, 0);
    }

#pragma unroll
    for (int mt = 0; mt < 4; mt++) {
#pragma unroll
        for (int r = 0; r < 4; r++) {
            int i = mt * 16 + quad * 4 + r;
            if (i < 49) {
                size_t g = gbase + (i / 7) * 56 + (i % 7);
#pragma unroll
                for (int nt = 0; nt < 2; nt++) {
                    size_t adr = g * CDIM + h * 32 + nt * 16 + l16;
                    x1[adr] = X[adr] + o[mt][nt][r];
                }
            }
        }
    }
}

// ---------------- launcher ----------------
// Base layout (proven): qkv_wt | fc1_wt | fc2_wt | xn | union(qkvb, hbuf) = 258,342,912 B.
// Tail (fused path, 34,816 B): c12p[16*256] f2 | c12[256] f2.
extern "C" void kernel_launch(void* const* d_in, const int* in_sizes, int n_in,
                              void* d_out, int out_size, void* d_ws, size_t ws_size,
                              hipStream_t stream) {
    const float* x      = (const float*)d_in[0];
    const float* ln1_g  = (const float*)d_in[1];
    const float* ln1_b  = (const float*)d_in[2];
    const float* qkv_w  = (const float*)d_in[3];
    const float* qkv_b  = (const float*)d_in[4];
    const float* ln2_g  = (const float*)d_in[5];
    const float* ln2_b  = (const float*)d_in[6];
    const float* fc1_w  = (const float*)d_in[7];
    const float* fc1_b  = (const float*)d_in[8];
    const float* mlp_g  = (const float*)d_in[9];
    const float* mlp_b  = (const float*)d_in[10];
    const float* fc2_w  = (const float*)d_in[11];
    const float* fc2_b  = (const float*)d_in[12];
    float* out = (float*)d_out;

    char* ws = (char*)d_ws;
    bf16* qkv_wt = (bf16*)ws;  ws += (size_t)768 * 256 * 2;
    bf16* fc1_wt = (bf16*)ws;  ws += (size_t)1024 * 256 * 2;
    bf16* fc2_wt = (bf16*)ws;  ws += (size_t)256 * 1024 * 2;
    bf16* xn     = (bf16*)ws;  ws += (size_t)MROWS * CDIM * 2;   // reused as x1n
    bf16* qkvb   = (bf16*)ws;                                     // union with hbuf
    bf16* hbuf   = (bf16*)ws;  ws += (size_t)MROWS * HIDD * 2;

    const size_t base_bytes = (size_t)(ws - (char*)d_ws);
    const size_t tail_bytes = (size_t)16 * 256 * sizeof(float2) + (size_t)256 * sizeof(float2);
    const bool fuse = (ws_size >= base_bytes + tail_bytes);
    const int swz = fuse ? 0x38 : 0;

    float2* c12p = (float2*)ws;
    float2* c12  = c12p + 16 * 256;
    float* x1 = out;

    // weight prep (pre-swizzled on the fused path)
    wt_kernel<<<768,  256, 0, stream>>>(qkv_w, qkv_wt, 256, 768, nullptr, swz);
    wt_kernel<<<1024, 256, 0, stream>>>(fc1_w, fc1_wt, 256, 1024, nullptr, swz);
    wt_kernel<<<1024, 256, 0, stream>>>(fc2_w, fc2_wt, 1024, 256,
                                        fuse ? mlp_g : nullptr, swz);
    if (fuse) {
        c12_part_kernel<<<16, 256, 0, stream>>>(fc2_w, mlp_g, mlp_b, c12p);
        c12_red_kernel<<<1, 256, 0, stream>>>(c12p, c12);
    }

    ln_apply_f32_kernel<<<MROWS / 4, 256, 0, stream>>>(x, ln1_g, ln1_b, xn, swz);
    if (fuse)
        gemm_bt_kernel<0, true, bf16><<<dim3(768 / 128, MROWS / 128), 256, 0, stream>>>(
            xn, qkv_wt, qkv_b, nullptr, qkvb, 768, 256);
    else
        gemm_bt_kernel<0, false, bf16><<<dim3(768 / 128, MROWS / 128), 256, 0, stream>>>(
            xn, qkv_wt, qkv_b, nullptr, qkvb, 768, 256);
    attn_kernel<<<BATCH * 64 * 2, 256, 0, stream>>>(qkvb, x, x1);
    ln_apply_f32_kernel<<<MROWS / 4, 256, 0, stream>>>(x1, ln2_g, ln2_b, xn, swz);

    if (fuse) {
        mlp_fused_kernel<<<MROWS / 64, 256, 0, stream>>>(
            xn, fc1_wt, fc2_wt, fc1_b, fc2_b, x1, c12, out);
    } else {
        gemm_bt_kernel<1, false, bf16><<<dim3(HIDD / 128, MROWS / 128), 256, 0, stream>>>(
            xn, fc1_wt, fc1_b, nullptr, hbuf, HIDD, 256);
        ln_inplace_h_kernel<<<MROWS / 4, 256, 0, stream>>>(hbuf, mlp_g, mlp_b);
        gemm_bt_kernel<3, false, float><<<dim3(CDIM / 128, MROWS / 128), 256, 0, stream>>>(
            hbuf, fc2_wt, fc2_b, x1, out, CDIM, 1024);
    }
}